// Round 3
// baseline (215.965 us; speedup 1.0000x reference)
//
#include <hip/hip_runtime.h>
#include <hip/hip_fp16.h>

#define DEGCAP 64     // per-node capacity; deg ~ Poisson(16), P(deg>64) ~ 1e-17

typedef _Float16 half8 __attribute__((ext_vector_type(8)));
typedef float float4v __attribute__((ext_vector_type(4)));

// ---------------------------------------------------------------------------
// prep (grid-stride): x -> fp16 xh, zero per-node cursors, transpose weights
// to fp16 frag layout Wt[c][k] (c:0-63 = L cols, 64-127 = R cols).
__global__ __launch_bounds__(256) void prep(const float* __restrict__ x,
                                            _Float16* __restrict__ xh,
                                            int* __restrict__ gCursor,
                                            const float* __restrict__ w1l,
                                            const float* __restrict__ w1r,
                                            const float* __restrict__ w2l,
                                            const float* __restrict__ w2r,
                                            _Float16* __restrict__ Wt1,
                                            _Float16* __restrict__ Wt2, int N) {
    const int gtid = blockIdx.x * 256 + threadIdx.x;
    const int gstride = gridDim.x * 256;

    // x -> xh : 8 floats per thread-item (2x dwordx4 in, 1x dwordx4 out)
    const int nv = N * 16;   // N*128/8
    const float4* xf = (const float4*)x;
    for (int i = gtid; i < nv; i += gstride) {
        float4 a0 = xf[i * 2 + 0];
        float4 a1 = xf[i * 2 + 1];
        half8 h;
        h[0] = (_Float16)a0.x; h[1] = (_Float16)a0.y;
        h[2] = (_Float16)a0.z; h[3] = (_Float16)a0.w;
        h[4] = (_Float16)a1.x; h[5] = (_Float16)a1.y;
        h[6] = (_Float16)a1.z; h[7] = (_Float16)a1.w;
        ((half8*)xh)[i] = h;
    }
    for (int i = gtid; i < N; i += gstride) gCursor[i] = 0;
    for (int i = gtid; i < 128 * 128; i += gstride) {
        int c = i >> 7, k = i & 127;
        const float* W = (c < 64) ? w1l : w1r;
        Wt1[c * 128 + k] = (_Float16)W[k * 64 + (c & 63)];
    }
    for (int i = gtid; i < 128 * 64; i += gstride) {
        int c = i >> 6, k = i & 63;
        const float* W = (c < 64) ? w2l : w2r;
        Wt2[c * 64 + k] = (_Float16)W[k * 64 + (c & 63)];
    }
}

// ---------------------------------------------------------------------------
// direct per-node CSR scatter: one global atomic + 2B store per edge.
__global__ __launch_bounds__(256) void scatter(const int* __restrict__ src,
                                               const int* __restrict__ dst,
                                               int* __restrict__ gCursor,
                                               unsigned short* __restrict__ ssrc,
                                               int E) {
    const int gtid = blockIdx.x * 256 + threadIdx.x;
    const int gstride = gridDim.x * 256;
    for (int j = gtid; j < E; j += gstride) {
        int d = dst[j];
        int s = src[j];
        int pos = atomicAdd(&gCursor[d], 1);
        if (pos < DEGCAP)
            ssrc[(long long)d * DEGCAP + pos] = (unsigned short)s;
    }
}

// ---------------------------------------------------------------------------
// dual GEMM template, zero-LDS, fp16 A: C = A(MxK) * {Wl,Wr}(Kx64).
// All A fragments hoisted into registers BEFORE the MFMA block so the
// compiler keeps the loads in flight (round-2 post-mortem: sunk loads
// serialized the kernel at VGPR=44).
template <int K>
__global__ __launch_bounds__(256) void gemm_dual(const _Float16* __restrict__ Ah,
                                                 const _Float16* __restrict__ Wt,
                                                 unsigned short* __restrict__ Clh,
                                                 unsigned short* __restrict__ Trh,
                                                 int M) {
    constexpr int NS = K / 32;
    const int tid = threadIdx.x;
    const int row0 = blockIdx.x * 64;
    const int wv = tid >> 6;
    const int lane = tid & 63;
    const int qd = lane >> 4;
    const int lr = lane & 15;
    const int col = wv * 16 + lr;

    // B fragments: contiguous dwordx4 from transposed weights (L2-hit)
    half8 bl[NS], br[NS];
    #pragma unroll
    for (int s = 0; s < NS; ++s) {
        bl[s] = *(const half8*)&Wt[col * K + s * 32 + qd * 8];
        br[s] = *(const half8*)&Wt[(64 + col) * K + s * 32 + qd * 8];
    }

    // A fragments: one dwordx4 each, all issued before any MFMA
    half8 a[4][NS];
    #pragma unroll
    for (int i = 0; i < 4; ++i) {
        const int gr = row0 + i * 16 + lr;
        const bool ok = gr < M;
        const _Float16* Arow = &Ah[(long long)gr * K];
        #pragma unroll
        for (int s = 0; s < NS; ++s) {
            a[i][s] = ok ? *(const half8*)&Arow[s * 32 + qd * 8]
                         : (half8){0, 0, 0, 0, 0, 0, 0, 0};
        }
    }

    float4v accL[4], accR[4];
    #pragma unroll
    for (int i = 0; i < 4; ++i) {
        accL[i] = (float4v){0.f, 0.f, 0.f, 0.f};
        accR[i] = (float4v){0.f, 0.f, 0.f, 0.f};
    }

    #pragma unroll
    for (int i = 0; i < 4; ++i) {
        #pragma unroll
        for (int s = 0; s < NS; ++s) {
            accL[i] = __builtin_amdgcn_mfma_f32_16x16x32_f16(a[i][s], bl[s], accL[i], 0, 0, 0);
            accR[i] = __builtin_amdgcn_mfma_f32_16x16x32_f16(a[i][s], br[s], accR[i], 0, 0, 0);
        }
    }

    #pragma unroll
    for (int i = 0; i < 4; ++i) {
        #pragma unroll
        for (int rg = 0; rg < 4; ++rg) {
            int gr = row0 + i * 16 + qd * 4 + rg;
            if (gr < M) {
                Clh[(long long)gr * 64 + col] = __half_as_ushort(__float2half_rn(accL[i][rg]));
                Trh[(long long)gr * 64 + col] = __half_as_ushort(__float2half_rn(accR[i][rg]));
            }
        }
    }
}

// ---------------------------------------------------------------------------
// pull aggregation + combine: one wave per dst node, half2 channel packing,
// 2 edges/step, x8 unroll. deg <= DEGCAP so the edge list is one 64-chunk.
// All __shfl wave-uniform (shfl from an exited lane is undefined).
template <bool OUTH>
__global__ __launch_bounds__(256) void agg_combine(const unsigned int* __restrict__ tl2,
                                                   const unsigned int* __restrict__ trh2,
                                                   const float* __restrict__ bias,
                                                   const int* __restrict__ cnt,
                                                   const unsigned short* __restrict__ ssrc,
                                                   void* __restrict__ outv, int N) {
    int w = (blockIdx.x * 256 + threadIdx.x) >> 6;
    int lane = threadIdx.x & 63;
    if (w >= N) return;
    int deg = cnt[w];
    int n = deg < DEGCAP ? deg : DEGCAP;
    int c2 = lane & 31;
    int half = lane >> 5;

    int sid = (lane < n) ? (int)ssrc[(long long)w * DEGCAP + lane] : 0;

    float x0 = 0.f, y0 = 0.f, x1 = 0.f, y1 = 0.f;
    float x2 = 0.f, y2 = 0.f, x3 = 0.f, y3 = 0.f;
    float x4 = 0.f, y4 = 0.f, x5 = 0.f, y5 = 0.f;
    float x6 = 0.f, y6 = 0.f, x7 = 0.f, y7 = 0.f;

    int jj = 0;
    for (; jj + 16 <= n; jj += 16) {
        int e0 = __shfl(sid, jj + 0 + half, 64);
        int e1 = __shfl(sid, jj + 2 + half, 64);
        int e2 = __shfl(sid, jj + 4 + half, 64);
        int e3 = __shfl(sid, jj + 6 + half, 64);
        int e4 = __shfl(sid, jj + 8 + half, 64);
        int e5 = __shfl(sid, jj + 10 + half, 64);
        int e6 = __shfl(sid, jj + 12 + half, 64);
        int e7 = __shfl(sid, jj + 14 + half, 64);
        unsigned int u0 = tl2[e0 * 32 + c2];
        unsigned int u1 = tl2[e1 * 32 + c2];
        unsigned int u2 = tl2[e2 * 32 + c2];
        unsigned int u3 = tl2[e3 * 32 + c2];
        unsigned int u4 = tl2[e4 * 32 + c2];
        unsigned int u5 = tl2[e5 * 32 + c2];
        unsigned int u6 = tl2[e6 * 32 + c2];
        unsigned int u7 = tl2[e7 * 32 + c2];
        float2 f0 = __half22float2(*(__half2*)&u0);
        float2 f1 = __half22float2(*(__half2*)&u1);
        float2 f2 = __half22float2(*(__half2*)&u2);
        float2 f3 = __half22float2(*(__half2*)&u3);
        float2 f4 = __half22float2(*(__half2*)&u4);
        float2 f5 = __half22float2(*(__half2*)&u5);
        float2 f6 = __half22float2(*(__half2*)&u6);
        float2 f7 = __half22float2(*(__half2*)&u7);
        x0 += f0.x; y0 += f0.y;  x1 += f1.x; y1 += f1.y;
        x2 += f2.x; y2 += f2.y;  x3 += f3.x; y3 += f3.y;
        x4 += f4.x; y4 += f4.y;  x5 += f5.x; y5 += f5.y;
        x6 += f6.x; y6 += f6.y;  x7 += f7.x; y7 += f7.y;
    }
    for (; jj + 8 <= n; jj += 8) {
        int e0 = __shfl(sid, jj + 0 + half, 64);
        int e1 = __shfl(sid, jj + 2 + half, 64);
        int e2 = __shfl(sid, jj + 4 + half, 64);
        int e3 = __shfl(sid, jj + 6 + half, 64);
        unsigned int u0 = tl2[e0 * 32 + c2];
        unsigned int u1 = tl2[e1 * 32 + c2];
        unsigned int u2 = tl2[e2 * 32 + c2];
        unsigned int u3 = tl2[e3 * 32 + c2];
        float2 f0 = __half22float2(*(__half2*)&u0);
        float2 f1 = __half22float2(*(__half2*)&u1);
        float2 f2 = __half22float2(*(__half2*)&u2);
        float2 f3 = __half22float2(*(__half2*)&u3);
        x0 += f0.x; y0 += f0.y;  x1 += f1.x; y1 += f1.y;
        x2 += f2.x; y2 += f2.y;  x3 += f3.x; y3 += f3.y;
    }
    for (; jj < n; jj += 2) {
        int e = __shfl(sid, jj + half, 64);
        if (jj + half < n) {
            unsigned int u = tl2[e * 32 + c2];
            float2 f = __half22float2(*(__half2*)&u);
            x0 += f.x; y0 += f.y;
        }
    }

    float sx = ((x0 + x1) + (x2 + x3)) + ((x4 + x5) + (x6 + x7));
    float sy = ((y0 + y1) + (y2 + y3)) + ((y4 + y5) + (y6 + y7));
    sx += __shfl_xor(sx, 32, 64);
    sy += __shfl_xor(sy, 32, 64);
    if (half == 0) {
        int c = c2 * 2;
        float d = (float)(deg > 1 ? deg : 1);
        unsigned int tu = trh2[(long long)w * 32 + c2];
        float2 t = __half22float2(*(__half2*)&tu);
        float2 bb = *(const float2*)&bias[c];
        float v0 = fmaxf(sx / d + t.x + bb.x, 0.f);
        float v1 = fmaxf(sy / d + t.y + bb.y, 0.f);
        if (OUTH) {
            __half2 hv = __floats2half2_rn(v0, v1);
            ((unsigned int*)outv)[(long long)w * 32 + c2] = *(unsigned int*)&hv;
        } else {
            ((float2*)outv)[(long long)w * 32 + c2] = make_float2(v0, v1);
        }
    }
}

extern "C" void kernel_launch(void* const* d_in, const int* in_sizes, int n_in,
                              void* d_out, int out_size, void* d_ws, size_t ws_size,
                              hipStream_t stream) {
    const float* x   = (const float*)d_in[0];
    const int*   ei  = (const int*)d_in[1];
    const float* w1l = (const float*)d_in[2];
    const float* w1r = (const float*)d_in[3];
    const float* b1  = (const float*)d_in[4];
    const float* w2l = (const float*)d_in[5];
    const float* w2r = (const float*)d_in[6];
    const float* b2  = (const float*)d_in[7];
    float* out = (float*)d_out;

    const int N = in_sizes[0] / 128;   // 50000
    const int E = in_sizes[1] / 2;     // 800000
    const int* src = ei;
    const int* dst = ei + E;

    // workspace layout (all 256B-aligned)
    auto alignup = [](size_t v) { return (v + 255) & ~(size_t)255; };
    char* p = (char*)d_ws;
    int* gCursor = (int*)p;                    p += alignup((size_t)N * sizeof(int));
    unsigned short* ssrc = (unsigned short*)p; p += alignup((size_t)N * DEGCAP * sizeof(unsigned short));
    const long long NC = (long long)N * 64;
    unsigned short* tlh = (unsigned short*)p;  p += alignup((size_t)NC * sizeof(unsigned short));
    unsigned short* trh = (unsigned short*)p;  p += alignup((size_t)NC * sizeof(unsigned short));
    unsigned short* hh  = (unsigned short*)p;  p += alignup((size_t)NC * sizeof(unsigned short));
    _Float16* xh  = (_Float16*)p;              p += alignup((size_t)N * 128 * sizeof(_Float16));
    _Float16* Wt1 = (_Float16*)p;              p += alignup(128 * 128 * sizeof(_Float16));
    _Float16* Wt2 = (_Float16*)p;              p += alignup(128 * 64 * sizeof(_Float16));

    const int gemmBlocks = (N + 63) / 64;              // 782
    const int aggBlocks = (int)((NC + 255) / 256);     // one wave per node

    prep<<<2048, 256, 0, stream>>>(x, xh, gCursor, w1l, w1r, w2l, w2r, Wt1, Wt2, N);

    scatter<<<400, 256, 0, stream>>>(src, dst, gCursor, ssrc, E);

    gemm_dual<128><<<gemmBlocks, 256, 0, stream>>>(xh, Wt1, tlh, trh, N);

    agg_combine<true><<<aggBlocks, 256, 0, stream>>>((const unsigned int*)tlh,
                                                     (const unsigned int*)trh,
                                                     b1, gCursor, ssrc, hh, N);

    gemm_dual<64><<<gemmBlocks, 256, 0, stream>>>((const _Float16*)hh, Wt2, tlh, trh, N);

    agg_combine<false><<<aggBlocks, 256, 0, stream>>>((const unsigned int*)tlh,
                                                      (const unsigned int*)trh,
                                                      b2, gCursor, ssrc, out, N);
}

// Round 4
// 179.010 us; speedup vs baseline: 1.2064x; 1.2064x over previous
//
#include <hip/hip_runtime.h>
#include <hip/hip_fp16.h>

#define DEGCAP 64     // per-node capacity; deg ~ Poisson(16), P(deg>64) ~ 1e-17
#define NB_MAX 256    // buckets = dst >> 8; N <= 65536
#define BCAP 5120     // bucket capacity (E/NB ~= 4081 expected, sigma ~64)
#define TILE 4000

typedef _Float16 half8 __attribute__((ext_vector_type(8)));
typedef float float4v __attribute__((ext_vector_type(4)));

// ---------------------------------------------------------------------------
// prep (grid-stride): x -> fp16 xh, zero bucket cursors, transpose weights
// to fp16 frag layout Wt[c][k] (c:0-63 = L cols, 64-127 = R cols).
__global__ __launch_bounds__(256) void prep(const float* __restrict__ x,
                                            _Float16* __restrict__ xh,
                                            int* __restrict__ bCursor,
                                            const float* __restrict__ w1l,
                                            const float* __restrict__ w1r,
                                            const float* __restrict__ w2l,
                                            const float* __restrict__ w2r,
                                            _Float16* __restrict__ Wt1,
                                            _Float16* __restrict__ Wt2, int N) {
    const int gtid = blockIdx.x * 256 + threadIdx.x;
    const int gstride = gridDim.x * 256;

    const int nv = N * 16;   // N*128/8
    const float4* xf = (const float4*)x;
    for (int i = gtid; i < nv; i += gstride) {
        float4 a0 = xf[i * 2 + 0];
        float4 a1 = xf[i * 2 + 1];
        half8 h;
        h[0] = (_Float16)a0.x; h[1] = (_Float16)a0.y;
        h[2] = (_Float16)a0.z; h[3] = (_Float16)a0.w;
        h[4] = (_Float16)a1.x; h[5] = (_Float16)a1.y;
        h[6] = (_Float16)a1.z; h[7] = (_Float16)a1.w;
        ((half8*)xh)[i] = h;
    }
    if (gtid < NB_MAX) bCursor[gtid] = 0;
    for (int i = gtid; i < 128 * 128; i += gstride) {
        int c = i >> 7, k = i & 127;
        const float* W = (c < 64) ? w1l : w1r;
        Wt1[c * 128 + k] = (_Float16)W[k * 64 + (c & 63)];
    }
    for (int i = gtid; i < 128 * 64; i += gstride) {
        int c = i >> 6, k = i & 63;
        const float* W = (c < 64) ? w2l : w2r;
        Wt2[c * 64 + k] = (_Float16)W[k * 64 + (c & 63)];
    }
}

// ---------------------------------------------------------------------------
// dual GEMM body, zero-LDS, fp16 A: C = A(MxK) * {Wl,Wr}(Kx64).
// All A/B fragments hoisted into registers BEFORE the MFMA block (round-2
// post-mortem: sunk loads serialized the kernel at VGPR=44).
template <int K>
__device__ __forceinline__ void gemm_body(const _Float16* __restrict__ Ah,
                                          const _Float16* __restrict__ Wt,
                                          unsigned short* __restrict__ Clh,
                                          unsigned short* __restrict__ Trh,
                                          int M, int blk) {
    constexpr int NS = K / 32;
    const int tid = threadIdx.x;
    const int row0 = blk * 64;
    const int wv = tid >> 6;
    const int lane = tid & 63;
    const int qd = lane >> 4;
    const int lr = lane & 15;
    const int col = wv * 16 + lr;

    half8 bl[NS], br[NS];
    #pragma unroll
    for (int s = 0; s < NS; ++s) {
        bl[s] = *(const half8*)&Wt[col * K + s * 32 + qd * 8];
        br[s] = *(const half8*)&Wt[(64 + col) * K + s * 32 + qd * 8];
    }

    half8 a[4][NS];
    #pragma unroll
    for (int i = 0; i < 4; ++i) {
        const int gr = row0 + i * 16 + lr;
        const bool ok = gr < M;
        const _Float16* Arow = &Ah[(long long)gr * K];
        #pragma unroll
        for (int s = 0; s < NS; ++s) {
            a[i][s] = ok ? *(const half8*)&Arow[s * 32 + qd * 8]
                         : (half8){0, 0, 0, 0, 0, 0, 0, 0};
        }
    }

    float4v accL[4], accR[4];
    #pragma unroll
    for (int i = 0; i < 4; ++i) {
        accL[i] = (float4v){0.f, 0.f, 0.f, 0.f};
        accR[i] = (float4v){0.f, 0.f, 0.f, 0.f};
    }

    #pragma unroll
    for (int i = 0; i < 4; ++i) {
        #pragma unroll
        for (int s = 0; s < NS; ++s) {
            accL[i] = __builtin_amdgcn_mfma_f32_16x16x32_f16(a[i][s], bl[s], accL[i], 0, 0, 0);
            accR[i] = __builtin_amdgcn_mfma_f32_16x16x32_f16(a[i][s], br[s], accR[i], 0, 0, 0);
        }
    }

    #pragma unroll
    for (int i = 0; i < 4; ++i) {
        #pragma unroll
        for (int rg = 0; rg < 4; ++rg) {
            int gr = row0 + i * 16 + qd * 4 + rg;
            if (gr < M) {
                Clh[(long long)gr * 64 + col] = __half_as_ushort(__float2half_rn(accL[i][rg]));
                Trh[(long long)gr * 64 + col] = __half_as_ushort(__float2half_rn(accR[i][rg]));
            }
        }
    }
}

// ---------------------------------------------------------------------------
// FUSED: blocks [0, scatterBlocks) run bucket-scatter phase 1 (coalesced
// packed writes to per-(block,bucket) reservations -- kills the 45 MB
// write-amplification of direct random 2B stores, round-3 post-mortem);
// the rest run the layer-1 dual GEMM. Independent work overlapped.
__global__ __launch_bounds__(256) void fused_scatter_gemm1(
        const int* __restrict__ src, const int* __restrict__ dst,
        int* __restrict__ bCursor, unsigned int* __restrict__ gPacked,
        int E, int NB, int scatterBlocks,
        const _Float16* __restrict__ Ah, const _Float16* __restrict__ Wt1,
        unsigned short* __restrict__ Clh, unsigned short* __restrict__ Trh,
        int M) {
    __shared__ __align__(16) char smem[22048];
    const int tid = threadIdx.x;

    if ((int)blockIdx.x < scatterBlocks) {
        unsigned int* spv = (unsigned int*)smem;            // 16000 B
        unsigned char* sbuk = (unsigned char*)(smem + 16000); // 4000 B
        int* hist = (int*)(smem + 20000);                   // 1024 B
        int* cur  = (int*)(smem + 21024);                   // 1024 B

        const int t0 = blockIdx.x * TILE;
        const int len = (E - t0) < TILE ? (E - t0) : TILE;

        hist[tid] = 0;
        __syncthreads();
        for (int j = tid; j < len; j += 256) {
            int d = dst[t0 + j];
            int s = src[t0 + j];
            int b = d >> 8;
            sbuk[j] = (unsigned char)b;
            spv[j] = ((unsigned int)(d & 255) << 17) | (unsigned int)s;
            atomicAdd(&hist[b], 1);
        }
        __syncthreads();
        if (tid < NB && hist[tid] > 0)
            cur[tid] = tid * BCAP + atomicAdd(&bCursor[tid], hist[tid]);
        __syncthreads();
        for (int j = tid; j < len; j += 256) {
            int b = sbuk[j];
            int pos = atomicAdd(&cur[b], 1);
            if (pos < (b + 1) * BCAP) gPacked[pos] = spv[j];
        }
    } else {
        gemm_body<128>(Ah, Wt1, Clh, Trh, M, (int)blockIdx.x - scatterBlocks);
    }
}

// ---------------------------------------------------------------------------
// bucket_build: one block per bucket (256 nodes, ~4096 entries, 32 KB ssrc
// region stays L2-resident -> coalesced-on-eviction writes). No prefix sum:
// LDS atomic per-node counters place entries directly; sum order irrelevant.
__global__ __launch_bounds__(256) void bucket_build(const unsigned int* __restrict__ gPacked,
                                                    const int* __restrict__ bCursor,
                                                    int* __restrict__ deg,
                                                    unsigned short* __restrict__ ssrc,
                                                    int N) {
    __shared__ int cnt[256];
    const int tid = threadIdx.x;
    const int b = blockIdx.x;
    const int base = b * BCAP;
    int C = bCursor[b];
    if (C > BCAP) C = BCAP;

    cnt[tid] = 0;
    __syncthreads();
    for (int j = tid; j < C; j += 256) {
        unsigned int v = gPacked[base + j];
        int ln = v >> 17;
        int pos = atomicAdd(&cnt[ln], 1);
        if (pos < DEGCAP)
            ssrc[(long long)(b * 256 + ln) * DEGCAP + pos] = (unsigned short)(v & 0x1FFFFu);
    }
    __syncthreads();
    int node = b * 256 + tid;
    if (node < N) deg[node] = cnt[tid] < DEGCAP ? cnt[tid] : DEGCAP;
}

// ---------------------------------------------------------------------------
// layer-2 dual GEMM wrapper
__global__ __launch_bounds__(256) void gemm2(const _Float16* __restrict__ Ah,
                                             const _Float16* __restrict__ Wt2,
                                             unsigned short* __restrict__ Clh,
                                             unsigned short* __restrict__ Trh,
                                             int M) {
    gemm_body<64>(Ah, Wt2, Clh, Trh, M, (int)blockIdx.x);
}

// ---------------------------------------------------------------------------
// pull aggregation + combine: one wave per dst node, half2 channel packing,
// 2 edges/step, x8 unroll. deg <= DEGCAP so the edge list is one 64-chunk.
// All __shfl wave-uniform (shfl from an exited lane is undefined).
template <bool OUTH>
__global__ __launch_bounds__(256) void agg_combine(const unsigned int* __restrict__ tl2,
                                                   const unsigned int* __restrict__ trh2,
                                                   const float* __restrict__ bias,
                                                   const int* __restrict__ deg_,
                                                   const unsigned short* __restrict__ ssrc,
                                                   void* __restrict__ outv, int N) {
    int w = (blockIdx.x * 256 + threadIdx.x) >> 6;
    int lane = threadIdx.x & 63;
    if (w >= N) return;
    int deg = deg_[w];
    int n = deg < DEGCAP ? deg : DEGCAP;
    int c2 = lane & 31;
    int half = lane >> 5;

    int sid = (lane < n) ? (int)ssrc[(long long)w * DEGCAP + lane] : 0;

    float x0 = 0.f, y0 = 0.f, x1 = 0.f, y1 = 0.f;
    float x2 = 0.f, y2 = 0.f, x3 = 0.f, y3 = 0.f;
    float x4 = 0.f, y4 = 0.f, x5 = 0.f, y5 = 0.f;
    float x6 = 0.f, y6 = 0.f, x7 = 0.f, y7 = 0.f;

    int jj = 0;
    for (; jj + 16 <= n; jj += 16) {
        int e0 = __shfl(sid, jj + 0 + half, 64);
        int e1 = __shfl(sid, jj + 2 + half, 64);
        int e2 = __shfl(sid, jj + 4 + half, 64);
        int e3 = __shfl(sid, jj + 6 + half, 64);
        int e4 = __shfl(sid, jj + 8 + half, 64);
        int e5 = __shfl(sid, jj + 10 + half, 64);
        int e6 = __shfl(sid, jj + 12 + half, 64);
        int e7 = __shfl(sid, jj + 14 + half, 64);
        unsigned int u0 = tl2[e0 * 32 + c2];
        unsigned int u1 = tl2[e1 * 32 + c2];
        unsigned int u2 = tl2[e2 * 32 + c2];
        unsigned int u3 = tl2[e3 * 32 + c2];
        unsigned int u4 = tl2[e4 * 32 + c2];
        unsigned int u5 = tl2[e5 * 32 + c2];
        unsigned int u6 = tl2[e6 * 32 + c2];
        unsigned int u7 = tl2[e7 * 32 + c2];
        float2 f0 = __half22float2(*(__half2*)&u0);
        float2 f1 = __half22float2(*(__half2*)&u1);
        float2 f2 = __half22float2(*(__half2*)&u2);
        float2 f3 = __half22float2(*(__half2*)&u3);
        float2 f4 = __half22float2(*(__half2*)&u4);
        float2 f5 = __half22float2(*(__half2*)&u5);
        float2 f6 = __half22float2(*(__half2*)&u6);
        float2 f7 = __half22float2(*(__half2*)&u7);
        x0 += f0.x; y0 += f0.y;  x1 += f1.x; y1 += f1.y;
        x2 += f2.x; y2 += f2.y;  x3 += f3.x; y3 += f3.y;
        x4 += f4.x; y4 += f4.y;  x5 += f5.x; y5 += f5.y;
        x6 += f6.x; y6 += f6.y;  x7 += f7.x; y7 += f7.y;
    }
    for (; jj + 8 <= n; jj += 8) {
        int e0 = __shfl(sid, jj + 0 + half, 64);
        int e1 = __shfl(sid, jj + 2 + half, 64);
        int e2 = __shfl(sid, jj + 4 + half, 64);
        int e3 = __shfl(sid, jj + 6 + half, 64);
        unsigned int u0 = tl2[e0 * 32 + c2];
        unsigned int u1 = tl2[e1 * 32 + c2];
        unsigned int u2 = tl2[e2 * 32 + c2];
        unsigned int u3 = tl2[e3 * 32 + c2];
        float2 f0 = __half22float2(*(__half2*)&u0);
        float2 f1 = __half22float2(*(__half2*)&u1);
        float2 f2 = __half22float2(*(__half2*)&u2);
        float2 f3 = __half22float2(*(__half2*)&u3);
        x0 += f0.x; y0 += f0.y;  x1 += f1.x; y1 += f1.y;
        x2 += f2.x; y2 += f2.y;  x3 += f3.x; y3 += f3.y;
    }
    for (; jj < n; jj += 2) {
        int e = __shfl(sid, jj + half, 64);
        if (jj + half < n) {
            unsigned int u = tl2[e * 32 + c2];
            float2 f = __half22float2(*(__half2*)&u);
            x0 += f.x; y0 += f.y;
        }
    }

    float sx = ((x0 + x1) + (x2 + x3)) + ((x4 + x5) + (x6 + x7));
    float sy = ((y0 + y1) + (y2 + y3)) + ((y4 + y5) + (y6 + y7));
    sx += __shfl_xor(sx, 32, 64);
    sy += __shfl_xor(sy, 32, 64);
    if (half == 0) {
        int c = c2 * 2;
        float d = (float)(deg > 1 ? deg : 1);
        unsigned int tu = trh2[(long long)w * 32 + c2];
        float2 t = __half22float2(*(__half2*)&tu);
        float2 bb = *(const float2*)&bias[c];
        float v0 = fmaxf(sx / d + t.x + bb.x, 0.f);
        float v1 = fmaxf(sy / d + t.y + bb.y, 0.f);
        if (OUTH) {
            __half2 hv = __floats2half2_rn(v0, v1);
            ((unsigned int*)outv)[(long long)w * 32 + c2] = *(unsigned int*)&hv;
        } else {
            ((float2*)outv)[(long long)w * 32 + c2] = make_float2(v0, v1);
        }
    }
}

extern "C" void kernel_launch(void* const* d_in, const int* in_sizes, int n_in,
                              void* d_out, int out_size, void* d_ws, size_t ws_size,
                              hipStream_t stream) {
    const float* x   = (const float*)d_in[0];
    const int*   ei  = (const int*)d_in[1];
    const float* w1l = (const float*)d_in[2];
    const float* w1r = (const float*)d_in[3];
    const float* b1  = (const float*)d_in[4];
    const float* w2l = (const float*)d_in[5];
    const float* w2r = (const float*)d_in[6];
    const float* b2  = (const float*)d_in[7];
    float* out = (float*)d_out;

    const int N = in_sizes[0] / 128;   // 50000
    const int E = in_sizes[1] / 2;     // 800000
    const int* src = ei;
    const int* dst = ei + E;
    const int NB = (N + 255) >> 8;     // 196 buckets

    // workspace layout (all 256B-aligned)
    auto alignup = [](size_t v) { return (v + 255) & ~(size_t)255; };
    char* p = (char*)d_ws;
    int* bCursor = (int*)p;                    p += alignup(NB_MAX * sizeof(int));
    int* deg     = (int*)p;                    p += alignup((size_t)N * sizeof(int));
    unsigned int* gPacked = (unsigned int*)p;  p += alignup((size_t)NB_MAX * BCAP * sizeof(unsigned int));
    unsigned short* ssrc = (unsigned short*)p; p += alignup((size_t)N * DEGCAP * sizeof(unsigned short));
    const long long NC = (long long)N * 64;
    unsigned short* tlh = (unsigned short*)p;  p += alignup((size_t)NC * sizeof(unsigned short));
    unsigned short* trh = (unsigned short*)p;  p += alignup((size_t)NC * sizeof(unsigned short));
    unsigned short* hh  = (unsigned short*)p;  p += alignup((size_t)NC * sizeof(unsigned short));
    _Float16* xh  = (_Float16*)p;              p += alignup((size_t)N * 128 * sizeof(_Float16));
    _Float16* Wt1 = (_Float16*)p;              p += alignup(128 * 128 * sizeof(_Float16));
    _Float16* Wt2 = (_Float16*)p;              p += alignup(128 * 64 * sizeof(_Float16));

    const int scatterBlocks = (E + TILE - 1) / TILE;   // 200
    const int gemmBlocks = (N + 63) / 64;              // 782
    const int aggBlocks = (int)((NC + 255) / 256);     // one wave per node

    prep<<<1024, 256, 0, stream>>>(x, xh, bCursor, w1l, w1r, w2l, w2r, Wt1, Wt2, N);

    // ---- fused: bucket-scatter phase 1 || layer-1 dual GEMM ----
    fused_scatter_gemm1<<<scatterBlocks + gemmBlocks, 256, 0, stream>>>(
        src, dst, bCursor, gPacked, E, NB, scatterBlocks,
        xh, Wt1, tlh, trh, N);

    bucket_build<<<NB, 256, 0, stream>>>(gPacked, bCursor, deg, ssrc, N);

    // ---- layer 1 aggregation ----
    agg_combine<true><<<aggBlocks, 256, 0, stream>>>((const unsigned int*)tlh,
                                                     (const unsigned int*)trh,
                                                     b1, deg, ssrc, hh, N);

    // ---- layer 2 ----
    gemm2<<<gemmBlocks, 256, 0, stream>>>((const _Float16*)hh, Wt2, tlh, trh, N);
    agg_combine<false><<<aggBlocks, 256, 0, stream>>>((const unsigned int*)tlh,
                                                      (const unsigned int*)trh,
                                                      b2, deg, ssrc, out, N);
}